// Round 1
// baseline (10039.431 us; speedup 1.0000x reference)
//
#include <hip/hip_runtime.h>
#include <hip/hip_bf16.h>

#define BB 512
#define TT 128
#define EE 64
#define HH 512
#define VV 100
#define NG 2048

__device__ __forceinline__ float sigm(float x) { return 1.0f / (1.0f + expf(-x)); }

// -------- precompute: P_vocab[v][n] = sum_e emb[v,e] * W0[e, n] --------
__global__ __launch_bounds__(256) void pv_kernel(
    const float* __restrict__ cemb, const float* __restrict__ W0,
    float* __restrict__ Pvocab) {
  int idx = blockIdx.x * 256 + threadIdx.x;  // 100*2048
  if (idx >= VV * NG) return;
  int v = idx >> 11, n = idx & (NG - 1);
  float acc = 0.f;
  for (int e = 0; e < EE; e++) acc += cemb[v * EE + e] * W0[e * NG + n];
  Pvocab[idx] = acc;
}

// -------- precompute: P_state[b][n] = b0[n] + sum_k state[b,k] * W0[64+k, n] --------
__global__ __launch_bounds__(256) void ps_kernel(
    const float* __restrict__ state, const float* __restrict__ W0,
    const float* __restrict__ b0v, float* __restrict__ Pstate) {
  const int nb = blockIdx.x & 7;           // 8 col tiles of 256
  const int bb0 = (blockIdx.x >> 3) * 16;  // 32 row tiles of 16
  const int tid = threadIdx.x;
  const int n = nb * 256 + tid;
  __shared__ float Slds[16][64];
  float acc[16];
  float bv = b0v[n];
  for (int i = 0; i < 16; i++) acc[i] = bv;
  for (int kc = 0; kc < HH; kc += 64) {
    __syncthreads();
    for (int i = 0; i < 4; i++) {
      int idx = tid + 256 * i;
      int r = idx >> 6, kk = idx & 63;
      Slds[r][kk] = state[(bb0 + r) * HH + kc + kk];
    }
    __syncthreads();
    for (int kk = 0; kk < 64; kk++) {
      float w = W0[(EE + kc + kk) * NG + n];
      for (int i = 0; i < 16; i++) acc[i] += Slds[i][kk] * w;
    }
  }
  for (int i = 0; i < 16; i++) Pstate[(bb0 + i) * NG + n] = acc[i];
}

// -------- phase kernel --------
// phase p: part 0 = LSTM layer0 step t=p (p in [0,127])
//          part 1 = LSTM layer1 step t=p-1 (p in [1,128])
// tile: 32 batch rows x 32 cells (=128 gate cols), 256 threads
__global__ __launch_bounds__(256) void phase_kernel(
    int p, const int* __restrict__ tok, const int* __restrict__ lens,
    const float* __restrict__ Pstate, const float* __restrict__ Pvocab,
    const float* __restrict__ W0, const float* __restrict__ W1,
    const float* __restrict__ b1,
    float* __restrict__ h0, float* __restrict__ h1,
    float* __restrict__ c0, float* __restrict__ c1,
    __hip_bfloat16* __restrict__ outs) {
  const int part = blockIdx.x >> 8;  // 256 blocks per part
  const int t = part ? (p - 1) : p;
  if (t < 0 || t >= TT) return;
  const int bidx = blockIdx.x & 255;
  const int b0r = (bidx >> 4) * 32;  // batch row base
  const int n0 = (bidx & 15) * 32;   // cell base
  const int tid = threadIdx.x;
  const int cc = tid & 31;   // cell within tile
  const int rg = tid >> 5;   // 0..7 row group (4 rows each)

  const int wr = p & 1, rdb = wr ^ 1;
  const float* h0rd = h0 + rdb * (BB * HH);
  float* h0wr = h0 + wr * (BB * HH);
  const float* h1rd = h1 + rdb * (BB * HH);
  float* h1wr = h1 + wr * (BB * HH);

  __shared__ float Alds[32][32];
  __shared__ float Blds[32][128];

  float acc[4][4];
  if (part == 0) {
    for (int i = 0; i < 4; i++) {
      int bb = b0r + rg * 4 + i;
      int tk = tok[bb * TT + t];
      const float* ps = Pstate + bb * NG + n0 + cc;
      const float* pv = Pvocab + tk * NG + n0 + cc;
      for (int g = 0; g < 4; g++) acc[i][g] = ps[g * HH] + pv[g * HH];
    }
  } else {
    for (int g = 0; g < 4; g++) {
      float bv = b1[n0 + cc + g * HH];
      for (int i = 0; i < 4; i++) acc[i][g] = bv;
    }
  }

  const int npass = part ? 2 : 1;
  for (int pass = 0; pass < npass; pass++) {
    const float* Ap = part ? (pass ? h1rd : h0rd) : h0rd;
    const float* Wb = part ? (W1 + pass * HH * NG) : (W0 + 576 * NG);
    for (int k0 = 0; k0 < HH; k0 += 32) {
      __syncthreads();
      for (int i = 0; i < 4; i++) {  // A: 32x32
        int idx = tid + 256 * i;
        int r = idx >> 5, kk = idx & 31;
        Alds[r][kk] = Ap[(b0r + r) * HH + k0 + kk];
      }
      for (int i = 0; i < 16; i++) {  // B: 32x128 gate-block layout
        int idx = tid + 256 * i;
        int kk = idx >> 7, cj = idx & 127;
        Blds[kk][cj] = Wb[(k0 + kk) * NG + n0 + (cj & 31) + (cj >> 5) * HH];
      }
      __syncthreads();
      for (int kk = 0; kk < 32; kk++) {
        float a[4], bv[4];
        for (int i = 0; i < 4; i++) a[i] = Alds[rg * 4 + i][kk];
        for (int g = 0; g < 4; g++) bv[g] = Blds[kk][cc + 32 * g];
        for (int i = 0; i < 4; i++)
          for (int g = 0; g < 4; g++) acc[i][g] += a[i] * bv[g];
      }
    }
  }

  for (int i = 0; i < 4; i++) {
    int bb = b0r + rg * 4 + i;
    bool m = t < lens[bb];
    int n = n0 + cc;
    int sidx = bb * HH + n;
    float ig = acc[i][0], jg = acc[i][1], fg = acc[i][2], og = acc[i][3];
    if (part == 0) {
      float cp = c0[sidx];
      float nc = cp * sigm(fg + 1.0f) + sigm(ig) * tanhf(jg);
      float nh = tanhf(nc) * sigm(og);
      if (m) c0[sidx] = nc;
      h0wr[sidx] = m ? nh : h0rd[sidx];
    } else {
      float cp = c1[sidx];
      float nc = cp * sigm(fg + 1.0f) + sigm(ig) * tanhf(jg);
      float nh = tanhf(nc) * sigm(og);
      if (m) c1[sidx] = nc;
      h1wr[sidx] = m ? nh : h1rd[sidx];
      float ov = m ? nh : 0.0f;
      outs[(bb * TT + t) * HH + n] = __float2bfloat16(ov);
    }
  }
}

// -------- projection: out[bt, v] = bp[v] + sum_h outs[bt,h] * Wp[h,v] --------
__global__ __launch_bounds__(256) void proj_kernel(
    const __hip_bfloat16* __restrict__ outs, const float* __restrict__ Wp,
    const float* __restrict__ bp, float* __restrict__ out) {
  const int bt0 = blockIdx.x * 32;
  const int tid = threadIdx.x;
  const int c = tid & 127;
  const int rgp = tid >> 7;  // 0..1, 16 rows each
  __shared__ unsigned short Olds[32][64];
  float acc[16];
  float bpv = (c < VV) ? bp[c] : 0.f;
  for (int i = 0; i < 16; i++) acc[i] = bpv;
  for (int kc = 0; kc < HH; kc += 64) {
    __syncthreads();
    for (int i = 0; i < 8; i++) {
      int idx = tid + 256 * i;
      int r = idx >> 6, kk = idx & 63;
      Olds[r][kk] = ((const unsigned short*)outs)[(bt0 + r) * HH + kc + kk];
    }
    __syncthreads();
    for (int kk = 0; kk < 64; kk++) {
      float w = (c < VV) ? Wp[(kc + kk) * VV + c] : 0.f;
      for (int i = 0; i < 16; i++) {
        float a = __uint_as_float(((unsigned int)Olds[rgp * 16 + i][kk]) << 16);
        acc[i] += a * w;
      }
    }
  }
  if (c < VV) {
    for (int i = 0; i < 16; i++) out[(bt0 + rgp * 16 + i) * VV + c] = acc[i];
  }
}

extern "C" void kernel_launch(void* const* d_in, const int* in_sizes, int n_in,
                              void* d_out, int out_size, void* d_ws, size_t ws_size,
                              hipStream_t stream) {
  const int* tok = (const int*)d_in[0];
  const int* lens = (const int*)d_in[1];
  const float* state = (const float*)d_in[2];
  const float* cemb = (const float*)d_in[3];
  const float* W0 = (const float*)d_in[4];
  const float* b0 = (const float*)d_in[5];
  const float* W1 = (const float*)d_in[6];
  const float* b1 = (const float*)d_in[7];
  const float* Wp = (const float*)d_in[8];
  const float* bp = (const float*)d_in[9];
  float* out = (float*)d_out;

  float* Pstate = (float*)d_ws;                   // 512*2048
  float* Pvocab = Pstate + BB * NG;               // 100*2048
  float* h0 = Pvocab + VV * NG;                   // 2*512*512
  float* h1 = h0 + 2 * BB * HH;                   // 2*512*512
  float* c0 = h1 + 2 * BB * HH;                   // 512*512
  float* c1 = c0 + BB * HH;                       // 512*512
  __hip_bfloat16* outs = (__hip_bfloat16*)(c1 + BB * HH);  // B*T*H bf16

  // zero h0 (both bufs), h1 (both bufs), c0, c1 (contiguous 6 MB)
  hipMemsetAsync(h0, 0, (size_t)(2 * BB * HH + 2 * BB * HH + 2 * BB * HH) * sizeof(float), stream);

  pv_kernel<<<(VV * NG + 255) / 256, 256, 0, stream>>>(cemb, W0, Pvocab);
  ps_kernel<<<256, 256, 0, stream>>>(state, W0, b0, Pstate);

  for (int p = 0; p <= TT; p++) {
    phase_kernel<<<512, 256, 0, stream>>>(p, tok, lens, Pstate, Pvocab, W0, W1,
                                          b1, h0, h1, c0, c1, outs);
  }

  proj_kernel<<<(BB * TT) / 32, 256, 0, stream>>>(outs, Wp, bp, out);
}

// Round 3
// 5224.145 us; speedup vs baseline: 1.9217x; 1.9217x over previous
//
#include <hip/hip_runtime.h>
#include <hip/hip_bf16.h>

#define BB 512
#define TT 128
#define EE 64
#define HH 512
#define VV 100
#define NG 2048

typedef __attribute__((ext_vector_type(8))) short bf16x8;
typedef __attribute__((ext_vector_type(4))) float f32x4;

__device__ __forceinline__ float sigm(float x) { return 1.f / (1.f + expf(-x)); }
__device__ __forceinline__ float bf2f(unsigned short u) {
  return __uint_as_float(((unsigned)u) << 16);
}
__device__ __forceinline__ unsigned short f2bf(float x) {  // RNE
  unsigned u = __float_as_uint(x);
  return (unsigned short)((u + 0x7fffu + ((u >> 16) & 1u)) >> 16);
}
__device__ __forceinline__ void gl16(void* lds, const void* g) {
  __builtin_amdgcn_global_load_lds((const __attribute__((address_space(1))) void*)g,
                                   (__attribute__((address_space(3))) void*)lds, 16, 0, 0);
}

// -------- precompute: P_vocab[v][n] = sum_e emb[v,e] * W0[e, n] --------
__global__ __launch_bounds__(256) void pv_kernel(
    const float* __restrict__ cemb, const float* __restrict__ W0,
    float* __restrict__ Pvocab) {
  int idx = blockIdx.x * 256 + threadIdx.x;
  if (idx >= VV * NG) return;
  int v = idx >> 11, n = idx & (NG - 1);
  float acc = 0.f;
  for (int e = 0; e < EE; e++) acc += cemb[v * EE + e] * W0[e * NG + n];
  Pvocab[idx] = acc;
}

// -------- precompute: P_state[b][n] = b0[n] + sum_k state[b,k] * W0[64+k, n] --------
__global__ __launch_bounds__(256) void ps_kernel(
    const float* __restrict__ state, const float* __restrict__ W0,
    const float* __restrict__ b0v, float* __restrict__ Pstate) {
  const int nb = blockIdx.x & 7;
  const int bb0 = (blockIdx.x >> 3) * 16;
  const int tid = threadIdx.x;
  const int n = nb * 256 + tid;
  __shared__ float Slds[16][64];
  float acc[16];
  float bv = b0v[n];
  for (int i = 0; i < 16; i++) acc[i] = bv;
  for (int kc = 0; kc < HH; kc += 64) {
    __syncthreads();
    for (int i = 0; i < 4; i++) {
      int idx = tid + 256 * i;
      int r = idx >> 6, kk = idx & 63;
      Slds[r][kk] = state[(bb0 + r) * HH + kc + kk];
    }
    __syncthreads();
    for (int kk = 0; kk < 64; kk++) {
      float w = W0[(EE + kc + kk) * NG + n];
      for (int i = 0; i < 16; i++) acc[i] += Slds[i][kk] * w;
    }
  }
  for (int i = 0; i < 16; i++) Pstate[(bb0 + i) * NG + n] = acc[i];
}

// -------- weight convert to fragment-order bf16 hi/lo --------
// Wf layout: [ntile 16][kc nkch][hl 2][nfrag 8][lane 64][j 8]  (chunk = 8192 shorts)
// One thread per SOURCE element (4096 per chunk): writes hi and lo.
// element (k, cj): lane = (cj&15) | ((k>>3)&3)<<4, j = k&7, nfrag = cj>>4
// global col = ntile*32 + (cj&31) + (cj>>5)*HH
__global__ __launch_bounds__(256) void wconv_kernel(
    const float* __restrict__ W, int koff, unsigned short* __restrict__ Wf,
    int nkch) {
  int u = blockIdx.x * 256 + threadIdx.x;
  int j = u & 7;
  int lane = (u >> 3) & 63;
  int ni = (u >> 9) & 7;
  int kc = (u >> 12) & (nkch - 1);
  int ntile = (u >> 12) / nkch;
  if (ntile >= 16) return;  // defensive
  int q = lane >> 4, c15 = lane & 15;
  int cj = ni * 16 + c15;
  int k = kc * 32 + q * 8 + j;
  int col = ntile * 32 + (cj & 31) + (cj >> 5) * HH;
  float x = W[(size_t)(koff + k) * NG + col];
  unsigned short hi = f2bf(x);
  unsigned short lo = f2bf(x - bf2f(hi));
  size_t base = ((size_t)(ntile * nkch + kc)) * 8192 + ni * 512 + lane * 8 + j;
  Wf[base] = hi;
  Wf[base + 4096] = lo;
}

// -------- phase kernel --------
// phase p: part0 = layer0 step t=p; part1 = layer1 step t=p-1
// block: 64 batch rows x 128 gate-cols (32 cells x 4 gates, gate-major)
// 4 waves = 4 M-fragments of 16 rows; 16x16x32 bf16 MFMA; split hi/lo (3 products)
// h stored fragment-order: [mtile 8][kch 16][hl 2][mfrag 4][lane 64][8], 2 buffers
__global__ __launch_bounds__(256) void phase_kernel(
    int p, const int* __restrict__ tok, const int* __restrict__ lens,
    const float* __restrict__ Pstate, const float* __restrict__ Pvocab,
    const unsigned short* __restrict__ W0f, const unsigned short* __restrict__ W1f,
    const float* __restrict__ b1,
    unsigned short* __restrict__ h0f, unsigned short* __restrict__ h1f,
    float* __restrict__ c0, float* __restrict__ c1,
    unsigned short* __restrict__ outs) {
  const int part = blockIdx.x >> 7;
  const int t = part ? (p - 1) : p;
  if (t < 0 || t >= TT) return;
  const int bid = blockIdx.x & 127;
  // XCD-aware swizzle: blocks with bid%8==x get ntiles {2x, 2x+1} -> L2-resident weights
  const int x = bid & 7, r = bid >> 3;
  const int mb = r & 7;                   // 0..7  (64 rows)
  const int ntile = x * 2 + (r >> 3);     // 0..15 (32 cells)
  const int tid = threadIdx.x;
  const int w = tid >> 6;                 // wave = mfrag
  const int lane = tid & 63;
  const int c15 = lane & 15, q = lane >> 4;

  const int wr = p & 1, rd = wr ^ 1;
  const unsigned short* h0rd = h0f + (size_t)rd * 524288;
  const unsigned short* h1rd = h1f + (size_t)rd * 524288;
  unsigned short* h0wr = h0f + (size_t)wr * 524288;
  unsigned short* h1wr = h1f + (size_t)wr * 524288;

  __shared__ __align__(16) unsigned short ldsA[2 * 4096];  // [buf][hl 2][mfrag 4][lane][8]
  __shared__ __align__(16) unsigned short ldsB[2 * 8192];  // [buf][hl 2][nfrag 8][lane][8]

  f32x4 acc[8];
  if (part == 0) {
#pragma unroll
    for (int i = 0; i < 4; i++) {
      int row = mb * 64 + w * 16 + q * 4 + i;
      int tk = tok[row * TT + t];
      const float* ps = Pstate + (size_t)row * NG;
      const float* pv = Pvocab + (size_t)tk * NG;
#pragma unroll
      for (int ni = 0; ni < 8; ni++) {
        int cj = ni * 16 + c15;
        int col = ntile * 32 + (cj & 31) + (cj >> 5) * HH;
        acc[ni][i] = ps[col] + pv[col];
      }
    }
  } else {
#pragma unroll
    for (int ni = 0; ni < 8; ni++) {
      int cj = ni * 16 + c15;
      int col = ntile * 32 + (cj & 31) + (cj >> 5) * HH;
      float bv = b1[col];
#pragma unroll
      for (int i = 0; i < 4; i++) acc[ni][i] = bv;
    }
  }

  const int nk = part ? 32 : 16;
  const unsigned short* Wsrc = part ? W1f : W0f;

  auto stageK = [&](int kc, int buf) {
    const unsigned short* wg = Wsrc + (size_t)(ntile * nk + kc) * 8192;
#pragma unroll
    for (int i2 = 0; i2 < 4; i2++) {
      int wc = w * 4 + i2;  // 0..15 = hl*8 + nfrag
      gl16(&ldsB[buf * 8192 + wc * 512 + lane * 8], wg + wc * 512 + lane * 8);
    }
    const unsigned short* asrc;
    if (part == 0) asrc = h0rd + (size_t)(mb * 16 + kc) * 4096;
    else asrc = (kc < 16) ? (h0rd + (size_t)(mb * 16 + kc) * 4096)
                          : (h1rd + (size_t)(mb * 16 + kc - 16) * 4096);
#pragma unroll
    for (int i2 = 0; i2 < 2; i2++) {
      int wc = w + i2 * 4;  // 0..7 = hl*4 + mfrag
      gl16(&ldsA[buf * 4096 + wc * 512 + lane * 8], asrc + wc * 512 + lane * 8);
    }
  };

  stageK(0, 0);
  __syncthreads();
  for (int kc = 0; kc < nk; kc++) {
    const int buf = kc & 1;
    if (kc + 1 < nk) stageK(kc + 1, buf ^ 1);
    const int ab = buf * 4096 + w * 512 + lane * 8;
    bf16x8 ahi = *(const bf16x8*)&ldsA[ab];
    bf16x8 alo = *(const bf16x8*)&ldsA[ab + 2048];
#pragma unroll
    for (int ni = 0; ni < 8; ni++) {
      bf16x8 bhi = *(const bf16x8*)&ldsB[buf * 8192 + ni * 512 + lane * 8];
      bf16x8 blo = *(const bf16x8*)&ldsB[buf * 8192 + 4096 + ni * 512 + lane * 8];
      acc[ni] = __builtin_amdgcn_mfma_f32_16x16x32_bf16(ahi, bhi, acc[ni], 0, 0, 0);
      acc[ni] = __builtin_amdgcn_mfma_f32_16x16x32_bf16(ahi, blo, acc[ni], 0, 0, 0);
      acc[ni] = __builtin_amdgcn_mfma_f32_16x16x32_bf16(alo, bhi, acc[ni], 0, 0, 0);
    }
    __syncthreads();
  }

  // epilogue: LSTM cell update; thread owns 4 rows x 2 cells x all 4 gates
  float* cbuf = part ? c1 : c0;
  const unsigned short* hrd = part ? h1rd : h0rd;
  unsigned short* hwr = part ? h1wr : h0wr;
#pragma unroll
  for (int i = 0; i < 4; i++) {
    int row = mb * 64 + w * 16 + q * 4 + i;
    bool msk = t < lens[row];
#pragma unroll
    for (int cb = 0; cb < 2; cb++) {
      int cell = ntile * 32 + cb * 16 + c15;
      float ig = acc[cb][i], jg = acc[2 + cb][i];
      float fg = acc[4 + cb][i], og = acc[6 + cb][i];
      size_t sidx = (size_t)row * HH + cell;
      size_t hb = (size_t)(mb * 16 + ntile) * 4096 + (size_t)w * 512 +
                  (size_t)((q * 4 + i) | ((cb * 2 + (c15 >> 3)) << 4)) * 8 +
                  (c15 & 7);
      if (msk) {
        float cp = cbuf[sidx];
        float nc = cp * sigm(fg + 1.f) + sigm(ig) * tanhf(jg);
        float nh = tanhf(nc) * sigm(og);
        cbuf[sidx] = nc;
        unsigned short hh = f2bf(nh);
        unsigned short hl = f2bf(nh - bf2f(hh));
        hwr[hb] = hh;
        hwr[hb + 2048] = hl;
        if (part) outs[((size_t)row * TT + t) * HH + cell] = f2bf(nh);
      } else {
        hwr[hb] = hrd[hb];
        hwr[hb + 2048] = hrd[hb + 2048];
        if (part) outs[((size_t)row * TT + t) * HH + cell] = 0;
      }
    }
  }
}

// -------- projection --------
__global__ __launch_bounds__(256) void proj_kernel(
    const unsigned short* __restrict__ outs, const float* __restrict__ Wp,
    const float* __restrict__ bp, float* __restrict__ out) {
  const int bt0 = blockIdx.x * 32;
  const int tid = threadIdx.x;
  const int c = tid & 127;
  const int rgp = tid >> 7;
  __shared__ unsigned short Olds[32][64];
  float acc[16];
  float bpv = (c < VV) ? bp[c] : 0.f;
  for (int i = 0; i < 16; i++) acc[i] = bpv;
  for (int kc = 0; kc < HH; kc += 64) {
    __syncthreads();
    for (int i = 0; i < 8; i++) {
      int idx = tid + 256 * i;
      int rr = idx >> 6, kk = idx & 63;
      Olds[rr][kk] = outs[(size_t)(bt0 + rr) * HH + kc + kk];
    }
    __syncthreads();
    for (int kk = 0; kk < 64; kk++) {
      float wv = (c < VV) ? Wp[(kc + kk) * VV + c] : 0.f;
      for (int i = 0; i < 16; i++) {
        float a = bf2f(Olds[rgp * 16 + i][kk]);
        acc[i] += a * wv;
      }
    }
  }
  if (c < VV) {
    for (int i = 0; i < 16; i++) out[(size_t)(bt0 + rgp * 16 + i) * VV + c] = acc[i];
  }
}

extern "C" void kernel_launch(void* const* d_in, const int* in_sizes, int n_in,
                              void* d_out, int out_size, void* d_ws, size_t ws_size,
                              hipStream_t stream) {
  const int* tok = (const int*)d_in[0];
  const int* lens = (const int*)d_in[1];
  const float* state = (const float*)d_in[2];
  const float* cemb = (const float*)d_in[3];
  const float* W0 = (const float*)d_in[4];
  const float* b0 = (const float*)d_in[5];
  const float* W1 = (const float*)d_in[6];
  const float* b1 = (const float*)d_in[7];
  const float* Wp = (const float*)d_in[8];
  const float* bp = (const float*)d_in[9];
  float* out = (float*)d_out;

  char* wsp = (char*)d_ws;
  float* Pstate = (float*)wsp; wsp += (size_t)BB * NG * 4;          // 4 MB
  float* Pvocab = (float*)wsp; wsp += (size_t)VV * NG * 4;          // 800 KB
  unsigned short* W0f = (unsigned short*)wsp; wsp += (size_t)16 * 16 * 8192 * 2;  // 4 MB
  unsigned short* W1f = (unsigned short*)wsp; wsp += (size_t)16 * 32 * 8192 * 2;  // 8 MB
  unsigned short* h0f = (unsigned short*)wsp; wsp += (size_t)2 * 524288 * 2;      // 2 MB
  unsigned short* h1f = (unsigned short*)wsp; wsp += (size_t)2 * 524288 * 2;      // 2 MB
  float* c0 = (float*)wsp; wsp += (size_t)BB * HH * 4;              // 1 MB
  float* c1 = (float*)wsp; wsp += (size_t)BB * HH * 4;              // 1 MB
  unsigned short* outs = (unsigned short*)wsp;                      // 64 MB

  // zero h0f,h1f,c0,c1 (contiguous 6 MB)
  hipMemsetAsync(h0f, 0, (size_t)2 * 2097152 + (size_t)2 * 1048576, stream);

  pv_kernel<<<(VV * NG + 255) / 256, 256, 0, stream>>>(cemb, W0, Pvocab);
  ps_kernel<<<256, 256, 0, stream>>>(state, W0, b0, Pstate);
  // one thread per SOURCE element: 16*nkch*4096 threads
  wconv_kernel<<<(16 * 16 * 4096) / 256, 256, 0, stream>>>(W0, EE + HH, W0f, 16);
  wconv_kernel<<<(16 * 32 * 4096) / 256, 256, 0, stream>>>(W1, 0, W1f, 32);

  for (int p = 0; p <= TT; p++) {
    phase_kernel<<<256, 256, 0, stream>>>(p, tok, lens, Pstate, Pvocab, W0f, W1f,
                                          b1, h0f, h1f, c0, c1, outs);
  }

  proj_kernel<<<(BB * TT) / 32, 256, 0, stream>>>(outs, Wp, bp, out);
}